// Round 1
// baseline (539.600 us; speedup 1.0000x reference)
//
#include <hip/hip_runtime.h>
#include <math.h>

#define N_FFT 4096
#define HOP   1024
#define PAD   2048
#define NBINS 2049
#define NFRM  257
#define BATCH 8
#define TLEN  262144          // 2^18
#define M     2048            // complex FFT size (real-packed)
#define TWO_PI 6.2831853071795864769f

#define FTILE 4
#define NT2   65              // ceil(257/4)

__device__ __forceinline__ int reflect_idx(int s) {
    if (s < 0) s = -s;
    if (s >= TLEN) s = 2 * (TLEN - 1) - s;
    return s;
}

// ---------------- Kernel 1: windowed frame -> rfft (2049 complex bins) ----------------
__global__ __launch_bounds__(256) void stft_kernel(const float* __restrict__ x,
                                                   float2* __restrict__ spec) {
    __shared__ float2 zbuf[M];
    __shared__ float2 twid[M / 2];

    int wg = blockIdx.x;
    int f  = wg % NFRM;
    int ch = (wg / NFRM) & 1;
    int b  = wg / (NFRM * 2);
    const float* xc = x + ((size_t)b * 2 + ch) * TLEN;
    int tid = threadIdx.x;

    // twiddle table: twid[t] = exp(-2*pi*i*t/M)
    for (int t = tid; t < M / 2; t += 256) {
        float sv, cv;
        sincosf(-(TWO_PI * (float)t) / (float)M, &sv, &cv);
        twid[t] = make_float2(cv, sv);
    }

    // load + reflect-pad + Hann window, pack pairs into complex, bit-reversed store
    int base = f * HOP - PAD;
    for (int idx = tid; idx < M; idx += 256) {
        int n0 = 2 * idx, n1 = n0 + 1;
        float w0 = 0.5f - 0.5f * cosf((TWO_PI / (float)N_FFT) * (float)n0);
        float w1v = 0.5f - 0.5f * cosf((TWO_PI / (float)N_FFT) * (float)n1);
        float v0 = xc[reflect_idx(base + n0)] * w0;
        float v1 = xc[reflect_idx(base + n1)] * w1v;
        int r = __brev((unsigned)idx) >> 21;   // 11-bit reverse
        zbuf[r] = make_float2(v0, v1);
    }
    __syncthreads();

    // 11 radix-2 DIT stages, in place, input bit-reversed -> natural order out
    for (int s = 0; s < 11; s++) {
        int half = 1 << s;
        for (int t = tid; t < M / 2; t += 256) {
            int blk = t >> s;
            int pos = t & (half - 1);
            int i0 = (blk << (s + 1)) + pos;
            int i1 = i0 + half;
            float2 wv = twid[pos << (10 - s)];
            float2 u = zbuf[i0];
            float2 v = zbuf[i1];
            float tr = v.x * wv.x - v.y * wv.y;
            float ti = v.x * wv.y + v.y * wv.x;
            zbuf[i0] = make_float2(u.x + tr, u.y + ti);
            zbuf[i1] = make_float2(u.x - tr, u.y - ti);
        }
        __syncthreads();
    }

    // unpack real FFT: X[k], k = 0..2048
    float2* out = spec + ((size_t)(b * 2 + ch) * NFRM + f) * NBINS;
    for (int k = tid; k < NBINS; k += 256) {
        int ka = k & (M - 1);
        int kb = (M - k) & (M - 1);
        float2 Zk = zbuf[ka];
        float2 Zc = zbuf[kb];
        Zc.y = -Zc.y;                      // conj
        float ex = 0.5f * (Zk.x + Zc.x);
        float ey = 0.5f * (Zk.y + Zc.y);
        float dx = Zk.x - Zc.x;
        float dy = Zk.y - Zc.y;
        float ox = 0.5f * dy;              // O = -0.5i * (Zk - conj)
        float oy = -0.5f * dx;
        float sv, cv;
        sincosf(-(TWO_PI * (float)k) / (float)N_FFT, &sv, &cv);
        float xr = ex + cv * ox - sv * oy;
        float xi = ey + cv * oy + sv * ox;
        out[k] = make_float2(xr, xi);
    }
}

// ---------------- Kernel 2: context MLP -> per-frame mask ----------------
__global__ __launch_bounds__(256) void mlp_kernel(const float2* __restrict__ spec,
                                                  const float* __restrict__ w1,
                                                  const float* __restrict__ b1,
                                                  const float* __restrict__ w2,
                                                  const float* __restrict__ b2,
                                                  const float* __restrict__ w3,
                                                  const float* __restrict__ b3,
                                                  float* __restrict__ mask) {
    int b  = blockIdx.x / NT2;
    int f0 = (blockIdx.x % NT2) * FTILE;
    int tid = threadIdx.x;

    float acc[FTILE][15];
#pragma unroll
    for (int fi = 0; fi < FTILE; fi++)
#pragma unroll
        for (int j = 0; j < 15; j++) acc[fi][j] = 0.f;

    for (int bin = tid; bin < NBINS; bin += 256) {
        float2 L[8], R[8];
#pragma unroll
        for (int gi = 0; gi < 8; gi++) {
            int g = f0 - 2 + gi;
            bool v = (g >= 0) && (g < NFRM);
            L[gi] = v ? spec[((size_t)(b * 2 + 0) * NFRM + g) * NBINS + bin]
                      : make_float2(0.f, 0.f);
            R[gi] = v ? spec[((size_t)(b * 2 + 1) * NFRM + g) * NBINS + bin]
                      : make_float2(0.f, 0.f);
        }
        const float* wb = w1 + (size_t)bin * 300;
#pragma unroll
        for (int co = 0; co < 5; co++) {
            const float4* wr = (const float4*)(wb + co * 60);
            float wv[60];
#pragma unroll
            for (int q = 0; q < 15; q++) {
                float4 t4 = wr[q];
                wv[q * 4 + 0] = t4.x; wv[q * 4 + 1] = t4.y;
                wv[q * 4 + 2] = t4.z; wv[q * 4 + 3] = t4.w;
            }
#pragma unroll
            for (int fi = 0; fi < FTILE; fi++) {
                float2 Lv = L[fi + co];
                float2 Rv = R[fi + co];
#pragma unroll
                for (int j = 0; j < 15; j++) {
                    acc[fi][j] += Lv.x * wv[j] + Rv.x * wv[15 + j]
                                + Lv.y * wv[30 + j] + Rv.y * wv[45 + j];
                }
            }
        }
    }

    // wave-level shuffle reduce (64 lanes)
#pragma unroll
    for (int fi = 0; fi < FTILE; fi++)
#pragma unroll
        for (int j = 0; j < 15; j++) {
            float v = acc[fi][j];
            for (int off = 32; off > 0; off >>= 1) v += __shfl_down(v, off, 64);
            acc[fi][j] = v;
        }

    __shared__ float red[4][60];
    __shared__ float hsum[60];
    int lane = tid & 63;
    int wid  = tid >> 6;
    if (lane == 0) {
#pragma unroll
        for (int fi = 0; fi < FTILE; fi++)
#pragma unroll
            for (int j = 0; j < 15; j++) red[wid][fi * 15 + j] = acc[fi][j];
    }
    __syncthreads();
    if (tid < 60) hsum[tid] = red[0][tid] + red[1][tid] + red[2][tid] + red[3][tid];
    __syncthreads();

    if (tid < FTILE) {
        int f = f0 + tid;
        if (f < NFRM) {
            float h1[15], h2[10];
#pragma unroll
            for (int j = 0; j < 15; j++) {
                float v = hsum[tid * 15 + j] + b1[j];
                h1[j] = v > 0.f ? v : 0.f;
            }
#pragma unroll
            for (int k = 0; k < 10; k++) {
                float s = b2[k];
#pragma unroll
                for (int j = 0; j < 15; j++) s += h1[j] * w2[j * 10 + k];
                h2[k] = s > 0.f ? s : 0.f;
            }
            float v = b3[0];
#pragma unroll
            for (int k = 0; k < 10; k++) v += h2[k] * w3[k];
            mask[b * NFRM + f] = 1.f / (1.f + expf(-v));
        }
    }
}

// ---------------- Kernel 3: analytic masked ISTFT (overlap-add ratio) ----------------
__global__ __launch_bounds__(256) void ola_kernel(const float* __restrict__ x,
                                                  const float* __restrict__ mask,
                                                  float* __restrict__ out) {
    int idx = blockIdx.x * 256 + threadIdx.x;     // < BATCH*2*TLEN
    int t  = idx & (TLEN - 1);
    int bc = idx >> 18;                           // TLEN = 2^18
    int b  = bc >> 1;
    int tau = t + PAD;
    int hi = tau >> 10; if (hi > NFRM - 1) hi = NFRM - 1;
    int lo = (tau - 3072) >> 10; if (lo < 0) lo = 0;   // ceil((tau-4095)/1024)
    float s0 = 0.f, s1 = 0.f;
    const float* mb = mask + b * NFRM;
    for (int f = lo; f <= hi; f++) {
        int n = tau - (f << 10);
        float w = 0.5f - 0.5f * cosf((TWO_PI / (float)N_FFT) * (float)n);
        float w2v = w * w;
        s0 += w2v;
        s1 += mb[f] * w2v;
    }
    float denom = (s0 > 1e-11f) ? s0 : 1.0f;
    out[idx] = x[idx] * (s1 / denom);
}

// ---------------- launch ----------------
extern "C" void kernel_launch(void* const* d_in, const int* in_sizes, int n_in,
                              void* d_out, int out_size, void* d_ws, size_t ws_size,
                              hipStream_t stream) {
    const float* x  = (const float*)d_in[0];
    const float* w1 = (const float*)d_in[1];
    const float* b1 = (const float*)d_in[2];
    const float* w2 = (const float*)d_in[3];
    const float* b2 = (const float*)d_in[4];
    const float* w3 = (const float*)d_in[5];
    const float* b3 = (const float*)d_in[6];

    float2* spec = (float2*)d_ws;
    size_t spec_elems = (size_t)BATCH * 2 * NFRM * NBINS;
    float* mask = (float*)((char*)d_ws + spec_elems * sizeof(float2));
    float* out = (float*)d_out;

    stft_kernel<<<BATCH * 2 * NFRM, 256, 0, stream>>>(x, spec);
    mlp_kernel<<<BATCH * NT2, 256, 0, stream>>>(spec, w1, b1, w2, b2, w3, b3, mask);
    ola_kernel<<<(BATCH * 2 * TLEN) / 256, 256, 0, stream>>>(x, mask, out);
}

// Round 2
// 427.952 us; speedup vs baseline: 1.2609x; 1.2609x over previous
//
#include <hip/hip_runtime.h>
#include <math.h>

#define N_FFT 4096
#define HOP   1024
#define PAD   2048
#define NBINS 2049
#define NFRM  257
#define BATCH 8
#define TLEN  262144          // 2^18
#define M     2048            // complex FFT size (real-packed)
#define TWO_PI 6.2831853071795864769f

#define FTILE 4
#define NT2   65              // ceil(257/4)

__device__ __forceinline__ int reflect_idx(int s) {
    if (s < 0) s = -s;
    if (s >= TLEN) s = 2 * (TLEN - 1) - s;
    return s;
}

// ---------------- Kernel 1: windowed frame -> rfft (2049 complex bins) ----------------
__global__ __launch_bounds__(256) void stft_kernel(const float* __restrict__ x,
                                                   float2* __restrict__ spec) {
    __shared__ float2 zbuf[M];
    __shared__ float2 twid[M / 2];

    int wg = blockIdx.x;
    int f  = wg % NFRM;
    int ch = (wg / NFRM) & 1;
    int b  = wg / (NFRM * 2);
    const float* xc = x + ((size_t)b * 2 + ch) * TLEN;
    int tid = threadIdx.x;

    // twiddle table: twid[t] = exp(-2*pi*i*t/M)
    for (int t = tid; t < M / 2; t += 256) {
        float sv, cv;
        sincosf(-(TWO_PI * (float)t) / (float)M, &sv, &cv);
        twid[t] = make_float2(cv, sv);
    }

    // load + reflect-pad + Hann window, pack pairs into complex, bit-reversed store
    int base = f * HOP - PAD;
    for (int idx = tid; idx < M; idx += 256) {
        int n0 = 2 * idx, n1 = n0 + 1;
        float w0 = 0.5f - 0.5f * cosf((TWO_PI / (float)N_FFT) * (float)n0);
        float w1v = 0.5f - 0.5f * cosf((TWO_PI / (float)N_FFT) * (float)n1);
        float v0 = xc[reflect_idx(base + n0)] * w0;
        float v1 = xc[reflect_idx(base + n1)] * w1v;
        int r = __brev((unsigned)idx) >> 21;   // 11-bit reverse
        zbuf[r] = make_float2(v0, v1);
    }
    __syncthreads();

    // 11 radix-2 DIT stages, in place, input bit-reversed -> natural order out
    for (int s = 0; s < 11; s++) {
        int half = 1 << s;
        for (int t = tid; t < M / 2; t += 256) {
            int blk = t >> s;
            int pos = t & (half - 1);
            int i0 = (blk << (s + 1)) + pos;
            int i1 = i0 + half;
            float2 wv = twid[pos << (10 - s)];
            float2 u = zbuf[i0];
            float2 v = zbuf[i1];
            float tr = v.x * wv.x - v.y * wv.y;
            float ti = v.x * wv.y + v.y * wv.x;
            zbuf[i0] = make_float2(u.x + tr, u.y + ti);
            zbuf[i1] = make_float2(u.x - tr, u.y - ti);
        }
        __syncthreads();
    }

    // unpack real FFT: X[k], k = 0..2048
    float2* out = spec + ((size_t)(b * 2 + ch) * NFRM + f) * NBINS;
    for (int k = tid; k < NBINS; k += 256) {
        int ka = k & (M - 1);
        int kb = (M - k) & (M - 1);
        float2 Zk = zbuf[ka];
        float2 Zc = zbuf[kb];
        Zc.y = -Zc.y;                      // conj
        float ex = 0.5f * (Zk.x + Zc.x);
        float ey = 0.5f * (Zk.y + Zc.y);
        float dx = Zk.x - Zc.x;
        float dy = Zk.y - Zc.y;
        float ox = 0.5f * dy;              // O = -0.5i * (Zk - conj)
        float oy = -0.5f * dx;
        float sv, cv;
        sincosf(-(TWO_PI * (float)k) / (float)N_FFT, &sv, &cv);
        float xr = ex + cv * ox - sv * oy;
        float xi = ey + cv * oy + sv * ox;
        out[k] = make_float2(xr, xi);
    }
}

// ---------------- Kernel 2: context MLP -> per-frame mask ----------------
// No staging arrays: every w1 float4 is consumed directly by FMAs with
// compile-time-constant indexing (avoids the R0 scratch-spill disaster).
__global__ __launch_bounds__(256) void mlp_kernel(const float2* __restrict__ spec,
                                                  const float* __restrict__ w1,
                                                  const float* __restrict__ b1,
                                                  const float* __restrict__ w2,
                                                  const float* __restrict__ b2,
                                                  const float* __restrict__ w3,
                                                  const float* __restrict__ b3,
                                                  float* __restrict__ mask) {
    int b  = blockIdx.x / NT2;
    int f0 = (blockIdx.x % NT2) * FTILE;
    int tid = threadIdx.x;

    float acc[FTILE][15];
#pragma unroll
    for (int fi = 0; fi < FTILE; fi++)
#pragma unroll
        for (int j = 0; j < 15; j++) acc[fi][j] = 0.f;

    for (int bin = tid; bin < NBINS; bin += 256) {
        float2 L[8], R[8];
#pragma unroll
        for (int gi = 0; gi < 8; gi++) {
            int g = f0 - 2 + gi;
            bool v = (g >= 0) && (g < NFRM);
            L[gi] = v ? spec[((size_t)(b * 2 + 0) * NFRM + g) * NBINS + bin]
                      : make_float2(0.f, 0.f);
            R[gi] = v ? spec[((size_t)(b * 2 + 1) * NFRM + g) * NBINS + bin]
                      : make_float2(0.f, 0.f);
        }
        // w1 slab for this bin: 20 rows (5 ctx groups x 4 feats) x 15 outputs
        const float4* wr = (const float4*)(w1 + (size_t)bin * 300);
#pragma unroll
        for (int co = 0; co < 5; co++) {
#pragma unroll
            for (int q = 0; q < 15; q++) {
                float4 w = wr[co * 15 + q];
#pragma unroll
                for (int e = 0; e < 4; e++) {
                    int j  = q * 4 + e;          // 0..59 within group, compile-time
                    int c  = j / 15;             // feature: 0=Lr 1=Rr 2=Li 3=Ri
                    int jj = j % 15;             // output index
                    float we = (e == 0) ? w.x : (e == 1) ? w.y : (e == 2) ? w.z : w.w;
#pragma unroll
                    for (int fi = 0; fi < FTILE; fi++) {
                        float2 Lv = L[fi + co];
                        float2 Rv = R[fi + co];
                        float fv = (c == 0) ? Lv.x : (c == 1) ? Rv.x
                                 : (c == 2) ? Lv.y : Rv.y;
                        acc[fi][jj] += fv * we;
                    }
                }
            }
        }
    }

    // wave-level shuffle reduce (64 lanes)
#pragma unroll
    for (int fi = 0; fi < FTILE; fi++)
#pragma unroll
        for (int j = 0; j < 15; j++) {
            float v = acc[fi][j];
            for (int off = 32; off > 0; off >>= 1) v += __shfl_down(v, off, 64);
            acc[fi][j] = v;
        }

    __shared__ float red[4][60];
    __shared__ float hsum[60];
    int lane = tid & 63;
    int wid  = tid >> 6;
    if (lane == 0) {
#pragma unroll
        for (int fi = 0; fi < FTILE; fi++)
#pragma unroll
            for (int j = 0; j < 15; j++) red[wid][fi * 15 + j] = acc[fi][j];
    }
    __syncthreads();
    if (tid < 60) hsum[tid] = red[0][tid] + red[1][tid] + red[2][tid] + red[3][tid];
    __syncthreads();

    if (tid < FTILE) {
        int f = f0 + tid;
        if (f < NFRM) {
            float h1[15], h2[10];
#pragma unroll
            for (int j = 0; j < 15; j++) {
                float v = hsum[tid * 15 + j] + b1[j];
                h1[j] = v > 0.f ? v : 0.f;
            }
#pragma unroll
            for (int k = 0; k < 10; k++) {
                float s = b2[k];
#pragma unroll
                for (int j = 0; j < 15; j++) s += h1[j] * w2[j * 10 + k];
                h2[k] = s > 0.f ? s : 0.f;
            }
            float v = b3[0];
#pragma unroll
            for (int k = 0; k < 10; k++) v += h2[k] * w3[k];
            mask[b * NFRM + f] = 1.f / (1.f + expf(-v));
        }
    }
}

// ---------------- Kernel 3: analytic masked ISTFT (overlap-add ratio) ----------------
__global__ __launch_bounds__(256) void ola_kernel(const float* __restrict__ x,
                                                  const float* __restrict__ mask,
                                                  float* __restrict__ out) {
    int idx = blockIdx.x * 256 + threadIdx.x;     // < BATCH*2*TLEN
    int t  = idx & (TLEN - 1);
    int bc = idx >> 18;                           // TLEN = 2^18
    int b  = bc >> 1;
    int tau = t + PAD;
    int hi = tau >> 10; if (hi > NFRM - 1) hi = NFRM - 1;
    int lo = (tau - 3072) >> 10; if (lo < 0) lo = 0;   // ceil((tau-4095)/1024)
    float s0 = 0.f, s1 = 0.f;
    const float* mb = mask + b * NFRM;
    for (int f = lo; f <= hi; f++) {
        int n = tau - (f << 10);
        float w = 0.5f - 0.5f * cosf((TWO_PI / (float)N_FFT) * (float)n);
        float w2v = w * w;
        s0 += w2v;
        s1 += mb[f] * w2v;
    }
    float denom = (s0 > 1e-11f) ? s0 : 1.0f;
    out[idx] = x[idx] * (s1 / denom);
}

// ---------------- launch ----------------
extern "C" void kernel_launch(void* const* d_in, const int* in_sizes, int n_in,
                              void* d_out, int out_size, void* d_ws, size_t ws_size,
                              hipStream_t stream) {
    const float* x  = (const float*)d_in[0];
    const float* w1 = (const float*)d_in[1];
    const float* b1 = (const float*)d_in[2];
    const float* w2 = (const float*)d_in[3];
    const float* b2 = (const float*)d_in[4];
    const float* w3 = (const float*)d_in[5];
    const float* b3 = (const float*)d_in[6];

    float2* spec = (float2*)d_ws;
    size_t spec_elems = (size_t)BATCH * 2 * NFRM * NBINS;
    float* mask = (float*)((char*)d_ws + spec_elems * sizeof(float2));
    float* out = (float*)d_out;

    stft_kernel<<<BATCH * 2 * NFRM, 256, 0, stream>>>(x, spec);
    mlp_kernel<<<BATCH * NT2, 256, 0, stream>>>(spec, w1, b1, w2, b2, w3, b3, mask);
    ola_kernel<<<(BATCH * 2 * TLEN) / 256, 256, 0, stream>>>(x, mask, out);
}

// Round 3
// 303.972 us; speedup vs baseline: 1.7752x; 1.4079x over previous
//
#include <hip/hip_runtime.h>
#include <math.h>

#define N_FFT 4096
#define HOP   1024
#define PAD   2048
#define NBINS 2049
#define NFRM  257
#define BATCH 8
#define TLEN  262144          // 2^18
#define M     2048            // complex FFT size (real-packed)
#define TWO_PI 6.2831853071795864769f

#define FTILE 4
#define NT2   65              // ceil(257/4)
#define S_SPLIT 4
#define CHUNK 512
#define FPAD  260             // NT2*FTILE

__device__ __forceinline__ int reflect_idx(int s) {
    if (s < 0) s = -s;
    if (s >= TLEN) s = 2 * (TLEN - 1) - s;
    return s;
}

// ---------------- Kernel 0: transpose w1 -> w1t[row][bin][16] ----------------
__global__ __launch_bounds__(256) void transpose_w1_kernel(const float* __restrict__ w1,
                                                           float* __restrict__ w1t) {
    int i = blockIdx.x * 256 + threadIdx.x;
    if (i >= NBINS * 300) return;
    int bin = i / 300;
    int rj  = i - bin * 300;
    int row = rj / 15;
    int j   = rj - row * 15;
    w1t[((size_t)row * NBINS + bin) * 16 + j] = w1[i];
}

// ---------------- Kernel 1: windowed frame -> rfft (2049 complex bins) ----------------
__global__ __launch_bounds__(256) void stft_kernel(const float* __restrict__ x,
                                                   float2* __restrict__ spec) {
    __shared__ float2 zbuf[M];
    __shared__ float2 twid[M / 2];

    int wg = blockIdx.x;
    int f  = wg % NFRM;
    int ch = (wg / NFRM) & 1;
    int b  = wg / (NFRM * 2);
    const float* xc = x + ((size_t)b * 2 + ch) * TLEN;
    int tid = threadIdx.x;

    for (int t = tid; t < M / 2; t += 256) {
        float sv, cv;
        sincosf(-(TWO_PI * (float)t) / (float)M, &sv, &cv);
        twid[t] = make_float2(cv, sv);
    }

    int base = f * HOP - PAD;
    for (int idx = tid; idx < M; idx += 256) {
        int n0 = 2 * idx, n1 = n0 + 1;
        float w0 = 0.5f - 0.5f * cosf((TWO_PI / (float)N_FFT) * (float)n0);
        float w1v = 0.5f - 0.5f * cosf((TWO_PI / (float)N_FFT) * (float)n1);
        float v0 = xc[reflect_idx(base + n0)] * w0;
        float v1 = xc[reflect_idx(base + n1)] * w1v;
        int r = __brev((unsigned)idx) >> 21;   // 11-bit reverse
        zbuf[r] = make_float2(v0, v1);
    }
    __syncthreads();

    for (int s = 0; s < 11; s++) {
        int half = 1 << s;
        for (int t = tid; t < M / 2; t += 256) {
            int blk = t >> s;
            int pos = t & (half - 1);
            int i0 = (blk << (s + 1)) + pos;
            int i1 = i0 + half;
            float2 wv = twid[pos << (10 - s)];
            float2 u = zbuf[i0];
            float2 v = zbuf[i1];
            float tr = v.x * wv.x - v.y * wv.y;
            float ti = v.x * wv.y + v.y * wv.x;
            zbuf[i0] = make_float2(u.x + tr, u.y + ti);
            zbuf[i1] = make_float2(u.x - tr, u.y - ti);
        }
        __syncthreads();
    }

    float2* out = spec + ((size_t)(b * 2 + ch) * NFRM + f) * NBINS;
    for (int k = tid; k < NBINS; k += 256) {
        int ka = k & (M - 1);
        int kb = (M - k) & (M - 1);
        float2 Zk = zbuf[ka];
        float2 Zc = zbuf[kb];
        Zc.y = -Zc.y;
        float ex = 0.5f * (Zk.x + Zc.x);
        float ey = 0.5f * (Zk.y + Zc.y);
        float dx = Zk.x - Zc.x;
        float dy = Zk.y - Zc.y;
        float ox = 0.5f * dy;
        float oy = -0.5f * dx;
        float sv, cv;
        sincosf(-(TWO_PI * (float)k) / (float)N_FFT, &sv, &cv);
        float xr = ex + cv * ox - sv * oy;
        float xi = ey + cv * oy + sv * ox;
        out[k] = make_float2(xr, xi);
    }
}

// ---------------- Kernel 2: layer-1 partial sums (bin-split, coalesced w1t) --------
__global__ __launch_bounds__(256) void mlp_kernel(const float2* __restrict__ spec,
                                                  const float* __restrict__ w1t,
                                                  float* __restrict__ partial) {
    int blk = blockIdx.x;
    int ft  = blk % NT2;
    int b   = (blk / NT2) % BATCH;
    int s   = blk / (NT2 * BATCH);
    int f0  = ft * FTILE;
    int tid = threadIdx.x;
    int bin_lo = s * CHUNK;
    int bin_hi = (s == S_SPLIT - 1) ? NBINS : bin_lo + CHUNK;

    float acc[FTILE][15];
#pragma unroll
    for (int fi = 0; fi < FTILE; fi++)
#pragma unroll
        for (int j = 0; j < 15; j++) acc[fi][j] = 0.f;

    const float2* specb = spec + (size_t)(b * 2) * NFRM * NBINS;

    for (int bin = bin_lo + tid; bin < bin_hi; bin += 256) {
        float2 L[8], R[8];
#pragma unroll
        for (int g = 0; g < 8; g++) {
            int ga = f0 - 2 + g;
            bool v = (ga >= 0) && (ga < NFRM);
            L[g] = v ? specb[(size_t)ga * NBINS + bin] : make_float2(0.f, 0.f);
            R[g] = v ? specb[(size_t)(NFRM + ga) * NBINS + bin] : make_float2(0.f, 0.f);
        }
        const float* wt = w1t + (size_t)bin * 16;
#pragma unroll
        for (int co = 0; co < 5; co++) {
#pragma unroll
            for (int c = 0; c < 4; c++) {
                int row = co * 4 + c;
                const float4* wp = (const float4*)(wt + (size_t)row * NBINS * 16);
                float4 wa = wp[0], wb4 = wp[1], wc = wp[2], wd = wp[3];
                float wj[16];
                *(float4*)&wj[0]  = wa;
                *(float4*)&wj[4]  = wb4;
                *(float4*)&wj[8]  = wc;
                *(float4*)&wj[12] = wd;
#pragma unroll
                for (int fi = 0; fi < FTILE; fi++) {
                    float fv = (c == 0) ? L[fi + co].x
                             : (c == 1) ? R[fi + co].x
                             : (c == 2) ? L[fi + co].y
                                        : R[fi + co].y;
#pragma unroll
                    for (int j = 0; j < 15; j++) acc[fi][j] += fv * wj[j];
                }
            }
        }
    }

    // wave shuffle reduce (64 lanes)
#pragma unroll
    for (int fi = 0; fi < FTILE; fi++)
#pragma unroll
        for (int j = 0; j < 15; j++) {
            float v = acc[fi][j];
            for (int off = 32; off > 0; off >>= 1) v += __shfl_down(v, off, 64);
            acc[fi][j] = v;
        }

    __shared__ float red[4][60];
    int lane = tid & 63;
    int wid  = tid >> 6;
    if (lane == 0) {
#pragma unroll
        for (int fi = 0; fi < FTILE; fi++)
#pragma unroll
            for (int j = 0; j < 15; j++) red[wid][fi * 15 + j] = acc[fi][j];
    }
    __syncthreads();
    if (tid < 60) {
        float v = red[0][tid] + red[1][tid] + red[2][tid] + red[3][tid];
        int fi = tid / 15;
        int j  = tid - fi * 15;
        partial[((size_t)(s * BATCH + b) * FPAD + f0 + fi) * 15 + j] = v;
    }
}

// ---------------- Kernel 2b: combine partials + MLP 2/3 -> mask ----------------
__global__ __launch_bounds__(256) void combine_kernel(const float* __restrict__ partial,
                                                      const float* __restrict__ b1,
                                                      const float* __restrict__ w2,
                                                      const float* __restrict__ b2,
                                                      const float* __restrict__ w3,
                                                      const float* __restrict__ b3,
                                                      float* __restrict__ mask) {
    int fidx = blockIdx.x * 256 + threadIdx.x;
    if (fidx >= BATCH * NFRM) return;
    int b = fidx / NFRM;
    int f = fidx - b * NFRM;

    float h1[15];
#pragma unroll
    for (int j = 0; j < 15; j++) h1[j] = b1[j];
#pragma unroll
    for (int s = 0; s < S_SPLIT; s++) {
        const float* p = partial + ((size_t)(s * BATCH + b) * FPAD + f) * 15;
#pragma unroll
        for (int j = 0; j < 15; j++) h1[j] += p[j];
    }
#pragma unroll
    for (int j = 0; j < 15; j++) h1[j] = h1[j] > 0.f ? h1[j] : 0.f;

    float h2[10];
#pragma unroll
    for (int k = 0; k < 10; k++) {
        float sv = b2[k];
#pragma unroll
        for (int j = 0; j < 15; j++) sv += h1[j] * w2[j * 10 + k];
        h2[k] = sv > 0.f ? sv : 0.f;
    }
    float v = b3[0];
#pragma unroll
    for (int k = 0; k < 10; k++) v += h2[k] * w3[k];
    mask[fidx] = 1.f / (1.f + expf(-v));
}

// ---------------- Kernel 3: analytic masked ISTFT (overlap-add ratio) ----------------
__global__ __launch_bounds__(256) void ola_kernel(const float* __restrict__ x,
                                                  const float* __restrict__ mask,
                                                  float* __restrict__ out) {
    int idx = blockIdx.x * 256 + threadIdx.x;
    int t  = idx & (TLEN - 1);
    int bc = idx >> 18;
    int b  = bc >> 1;
    int tau = t + PAD;
    int hi = tau >> 10; if (hi > NFRM - 1) hi = NFRM - 1;
    int lo = (tau - 3072) >> 10; if (lo < 0) lo = 0;
    float s0 = 0.f, s1 = 0.f;
    const float* mb = mask + b * NFRM;
    for (int f = lo; f <= hi; f++) {
        int n = tau - (f << 10);
        float w = 0.5f - 0.5f * cosf((TWO_PI / (float)N_FFT) * (float)n);
        float w2v = w * w;
        s0 += w2v;
        s1 += mb[f] * w2v;
    }
    float denom = (s0 > 1e-11f) ? s0 : 1.0f;
    out[idx] = x[idx] * (s1 / denom);
}

// ---------------- launch ----------------
extern "C" void kernel_launch(void* const* d_in, const int* in_sizes, int n_in,
                              void* d_out, int out_size, void* d_ws, size_t ws_size,
                              hipStream_t stream) {
    const float* x  = (const float*)d_in[0];
    const float* w1 = (const float*)d_in[1];
    const float* b1 = (const float*)d_in[2];
    const float* w2 = (const float*)d_in[3];
    const float* b2 = (const float*)d_in[4];
    const float* w3 = (const float*)d_in[5];
    const float* b3 = (const float*)d_in[6];

    char* wsp = (char*)d_ws;
    float2* spec = (float2*)wsp;
    size_t spec_bytes = (size_t)BATCH * 2 * NFRM * NBINS * sizeof(float2);   // 67.4 MB
    float* mask = (float*)(wsp + spec_bytes);
    size_t mask_bytes = (size_t)BATCH * NFRM * sizeof(float);                // 8.2 KB (16B-mult)
    float* w1t = (float*)(wsp + spec_bytes + mask_bytes);
    size_t w1t_bytes = (size_t)20 * NBINS * 16 * sizeof(float);              // 2.62 MB
    float* partial = (float*)(wsp + spec_bytes + mask_bytes + w1t_bytes);    // 0.5 MB
    float* out = (float*)d_out;

    transpose_w1_kernel<<<(NBINS * 300 + 255) / 256, 256, 0, stream>>>(w1, w1t);
    stft_kernel<<<BATCH * 2 * NFRM, 256, 0, stream>>>(x, spec);
    mlp_kernel<<<S_SPLIT * BATCH * NT2, 256, 0, stream>>>(spec, w1t, partial);
    combine_kernel<<<(BATCH * NFRM + 255) / 256, 256, 0, stream>>>(partial, b1, w2, b2, w3, b3, mask);
    ola_kernel<<<(BATCH * 2 * TLEN) / 256, 256, 0, stream>>>(x, mask, out);
}

// Round 4
// 253.717 us; speedup vs baseline: 2.1268x; 1.1981x over previous
//
#include <hip/hip_runtime.h>
#include <math.h>

#define N_FFT 4096
#define HOP   1024
#define PAD   2048
#define NBINS 2049
#define NFRM  257
#define BATCH 8
#define TLEN  262144          // 2^18
#define M     2048            // complex FFT size (real-packed)
#define TWO_PI 6.2831853071795864769f

#define S_SPLIT 50
#define CK      41            // ceil(2049/50); 50*41 = 2050 >= 2049
#define USLAB   (8 * 75 * NFRM)   // floats per split-slab = 154200

__device__ __forceinline__ int reflect_idx(int s) {
    if (s < 0) s = -s;
    if (s >= TLEN) s = 2 * (TLEN - 1) - s;
    return s;
}

__device__ __forceinline__ unsigned short f2bf(float f) {
    unsigned int u = __float_as_uint(f);
    unsigned int r = (u + 0x7FFFu + ((u >> 16) & 1u)) >> 16;   // RTNE
    return (unsigned short)r;
}

// ---------------- Kernel T: trig tables (replaces per-block sincosf) ----------------
__global__ __launch_bounds__(256) void tables_kernel(float2* __restrict__ twid_g,
                                                     float* __restrict__ wtab,
                                                     float2* __restrict__ utw) {
    int i = blockIdx.x * 256 + threadIdx.x;
    if (i < M / 2) {
        float sv, cv;
        sincosf(-(TWO_PI * (float)i) / (float)M, &sv, &cv);
        twid_g[i] = make_float2(cv, sv);
    }
    if (i < N_FFT) {
        wtab[i] = 0.5f - 0.5f * cosf((TWO_PI / (float)N_FFT) * (float)i);
    }
    if (i < NBINS) {
        float sv, cv;
        sincosf(-(TWO_PI * (float)i) / (float)N_FFT, &sv, &cv);
        utw[i] = make_float2(cv, sv);
    }
}

// ---------------- Kernel 1: windowed frame -> rfft -> bf16 spec ----------------
// spec layout: uint per bin = (im_bf16 << 16) | re_bf16, at [(b*2+ch)*NFRM + f]*NBINS + k
__global__ __launch_bounds__(256) void stft_kernel(const float* __restrict__ x,
                                                   const float2* __restrict__ twid_g,
                                                   const float* __restrict__ wtab,
                                                   const float2* __restrict__ utw,
                                                   unsigned int* __restrict__ spec) {
    __shared__ float2 zbuf[M];
    __shared__ float2 twid[M / 2];

    int wg = blockIdx.x;
    int f  = wg % NFRM;
    int ch = (wg / NFRM) & 1;
    int b  = wg / (NFRM * 2);
    const float* xc = x + ((size_t)b * 2 + ch) * TLEN;
    int tid = threadIdx.x;

    for (int t = tid; t < M / 2; t += 256) twid[t] = twid_g[t];

    int base = f * HOP - PAD;
    const float2* wt2 = (const float2*)wtab;
    for (int idx = tid; idx < M; idx += 256) {
        float2 wv = wt2[idx];                 // window[2*idx], window[2*idx+1]
        int n0 = 2 * idx;
        float v0 = xc[reflect_idx(base + n0)] * wv.x;
        float v1 = xc[reflect_idx(base + n0 + 1)] * wv.y;
        int r = __brev((unsigned)idx) >> 21;  // 11-bit reverse
        zbuf[r] = make_float2(v0, v1);
    }
    __syncthreads();

    for (int s = 0; s < 11; s++) {
        int half = 1 << s;
        for (int t = tid; t < M / 2; t += 256) {
            int blk = t >> s;
            int pos = t & (half - 1);
            int i0 = (blk << (s + 1)) + pos;
            int i1 = i0 + half;
            float2 wv = twid[pos << (10 - s)];
            float2 u = zbuf[i0];
            float2 v = zbuf[i1];
            float tr = v.x * wv.x - v.y * wv.y;
            float ti = v.x * wv.y + v.y * wv.x;
            zbuf[i0] = make_float2(u.x + tr, u.y + ti);
            zbuf[i1] = make_float2(u.x - tr, u.y - ti);
        }
        __syncthreads();
    }

    unsigned int* out = spec + ((size_t)(b * 2 + ch) * NFRM + f) * NBINS;
    for (int k = tid; k < NBINS; k += 256) {
        int ka = k & (M - 1);
        int kb = (M - k) & (M - 1);
        float2 Zk = zbuf[ka];
        float2 Zc = zbuf[kb];
        Zc.y = -Zc.y;
        float ex = 0.5f * (Zk.x + Zc.x);
        float ey = 0.5f * (Zk.y + Zc.y);
        float dx = Zk.x - Zc.x;
        float dy = Zk.y - Zc.y;
        float ox = 0.5f * dy;
        float oy = -0.5f * dx;
        float2 tw = utw[k];
        float xr = ex + tw.x * ox - tw.y * oy;
        float xi = ey + tw.x * oy + tw.y * ox;
        out[k] = ((unsigned int)f2bf(xi) << 16) | (unsigned int)f2bf(xr);
    }
}

// ---------------- Kernel 2: U-form layer-1 partials (frame-per-lane) ----------------
// U[b,fr,g,j] = sum_{bin,c} feat[b,bin,fr,c] * w1[bin*300 + (g*4+c)*15 + j]
// Weights are wave-uniform -> scalar loads; each lane holds 75 f32 accumulators.
__global__ __launch_bounds__(320) void mlp_u_kernel(const unsigned int* __restrict__ spec,
                                                    const float* __restrict__ w1,
                                                    float* __restrict__ partial) {
    int blk = blockIdx.x;          // 0..399
    int b = blk & 7;
    int s = blk >> 3;              // 0..49
    int fr = threadIdx.x;          // 0..319 (frame)
    int frc = fr < NFRM ? fr : NFRM - 1;

    const unsigned int* Lrow = spec + ((size_t)(b * 2 + 0) * NFRM + frc) * NBINS;
    const unsigned int* Rrow = spec + ((size_t)(b * 2 + 1) * NFRM + frc) * NBINS;

    int klo = s * CK;
    int khi = klo + CK; if (khi > NBINS) khi = NBINS;

    float acc[5][15];
#pragma unroll
    for (int g = 0; g < 5; g++)
#pragma unroll
        for (int j = 0; j < 15; j++) acc[g][j] = 0.f;

    for (int bin = klo; bin < khi; ++bin) {
        unsigned int lv = Lrow[bin];
        unsigned int rv = Rrow[bin];
        float Lr = __uint_as_float(lv << 16);
        float Li = __uint_as_float(lv & 0xFFFF0000u);
        float Rr = __uint_as_float(rv << 16);
        float Ri = __uint_as_float(rv & 0xFFFF0000u);
        const float* wb = w1 + (size_t)bin * 300;
#pragma unroll
        for (int g = 0; g < 5; g++) {
#pragma unroll
            for (int c = 0; c < 4; c++) {
                float fv = (c == 0) ? Lr : (c == 1) ? Rr : (c == 2) ? Li : Ri;
                const float* wr = wb + (g * 4 + c) * 15;
#pragma unroll
                for (int j = 0; j < 15; j++) acc[g][j] += fv * wr[j];
            }
        }
    }

    if (fr < NFRM) {
        float* pbase = partial + (size_t)(s * 8 + b) * 75 * NFRM + fr;
#pragma unroll
        for (int g = 0; g < 5; g++)
#pragma unroll
            for (int j = 0; j < 15; j++)
                pbase[(size_t)(g * 15 + j) * NFRM] = acc[g][j];
    }
}

// ---------------- Kernel 2b: sum split partials -> U ----------------
__global__ __launch_bounds__(256) void combine1_kernel(const float* __restrict__ partial,
                                                       float* __restrict__ U) {
    int i = blockIdx.x * 256 + threadIdx.x;
    if (i >= USLAB) return;
    float v = 0.f;
    for (int s = 0; s < S_SPLIT; s++) v += partial[(size_t)s * USLAB + i];
    U[i] = v;
}

// ---------------- Kernel 2c: context-fold + MLP 2/3 -> mask ----------------
__global__ __launch_bounds__(256) void mask_kernel(const float* __restrict__ U,
                                                   const float* __restrict__ b1,
                                                   const float* __restrict__ w2,
                                                   const float* __restrict__ b2,
                                                   const float* __restrict__ w3,
                                                   const float* __restrict__ b3,
                                                   float* __restrict__ mask) {
    int i = blockIdx.x * 256 + threadIdx.x;
    if (i >= BATCH * NFRM) return;
    int b = i / NFRM;
    int f = i - b * NFRM;

    float h1[15];
#pragma unroll
    for (int j = 0; j < 15; j++) h1[j] = b1[j];
#pragma unroll
    for (int g = 0; g < 5; g++) {
        int fr = f - 2 + g;
        if (fr >= 0 && fr < NFRM) {
#pragma unroll
            for (int j = 0; j < 15; j++)
                h1[j] += U[(size_t)(b * 75 + g * 15 + j) * NFRM + fr];
        }
    }
#pragma unroll
    for (int j = 0; j < 15; j++) h1[j] = h1[j] > 0.f ? h1[j] : 0.f;

    float h2[10];
#pragma unroll
    for (int k = 0; k < 10; k++) {
        float sv = b2[k];
#pragma unroll
        for (int j = 0; j < 15; j++) sv += h1[j] * w2[j * 10 + k];
        h2[k] = sv > 0.f ? sv : 0.f;
    }
    float v = b3[0];
#pragma unroll
    for (int k = 0; k < 10; k++) v += h2[k] * w3[k];
    mask[i] = 1.f / (1.f + expf(-v));
}

// ---------------- Kernel 3: analytic masked ISTFT (overlap-add ratio) ----------------
__global__ __launch_bounds__(256) void ola_kernel(const float* __restrict__ x,
                                                  const float* __restrict__ mask,
                                                  const float* __restrict__ wtab,
                                                  float* __restrict__ out) {
    int idx = blockIdx.x * 256 + threadIdx.x;
    int t  = idx & (TLEN - 1);
    int bc = idx >> 18;
    int b  = bc >> 1;
    int tau = t + PAD;
    int hi = tau >> 10; if (hi > NFRM - 1) hi = NFRM - 1;
    int lo = (tau - 3072) >> 10; if (lo < 0) lo = 0;
    float s0 = 0.f, s1 = 0.f;
    const float* mb = mask + b * NFRM;
    for (int f = lo; f <= hi; f++) {
        int n = tau - (f << 10);
        float w = wtab[n];
        float w2v = w * w;
        s0 += w2v;
        s1 += mb[f] * w2v;
    }
    float denom = (s0 > 1e-11f) ? s0 : 1.0f;
    out[idx] = x[idx] * (s1 / denom);
}

// ---------------- launch ----------------
extern "C" void kernel_launch(void* const* d_in, const int* in_sizes, int n_in,
                              void* d_out, int out_size, void* d_ws, size_t ws_size,
                              hipStream_t stream) {
    const float* x  = (const float*)d_in[0];
    const float* w1 = (const float*)d_in[1];
    const float* b1 = (const float*)d_in[2];
    const float* w2 = (const float*)d_in[3];
    const float* b2 = (const float*)d_in[4];
    const float* w3 = (const float*)d_in[5];
    const float* b3 = (const float*)d_in[6];

    char* wsp = (char*)d_ws;
    size_t off = 0;
    auto alloc = [&](size_t bytes) { void* p = wsp + off; off = (off + bytes + 511) & ~(size_t)511; return p; };

    unsigned int* spec = (unsigned int*)alloc((size_t)BATCH * 2 * NFRM * NBINS * 4);   // 33.7 MB
    float* partial     = (float*)alloc((size_t)S_SPLIT * USLAB * 4);                   // 30.8 MB
    float* U           = (float*)alloc((size_t)USLAB * 4);                             // 0.62 MB
    float* mask        = (float*)alloc((size_t)BATCH * NFRM * 4);
    float2* twid_g     = (float2*)alloc((size_t)(M / 2) * 8);
    float* wtab        = (float*)alloc((size_t)N_FFT * 4);
    float2* utw        = (float2*)alloc((size_t)NBINS * 8);
    float* out = (float*)d_out;

    tables_kernel<<<16, 256, 0, stream>>>(twid_g, wtab, utw);
    stft_kernel<<<BATCH * 2 * NFRM, 256, 0, stream>>>(x, twid_g, wtab, utw, spec);
    mlp_u_kernel<<<8 * S_SPLIT, 320, 0, stream>>>(spec, w1, partial);
    combine1_kernel<<<(USLAB + 255) / 256, 256, 0, stream>>>(partial, U);
    mask_kernel<<<(BATCH * NFRM + 255) / 256, 256, 0, stream>>>(U, b1, w2, b2, w3, b3, mask);
    ola_kernel<<<(BATCH * 2 * TLEN) / 256, 256, 0, stream>>>(x, mask, wtab, out);
}